// Round 1
// baseline (118.550 us; speedup 1.0000x reference)
//
#include <hip/hip_runtime.h>

// Self-attention (SAGAN-style): B=8, C=64, H=W=64 -> N=4096, E=C/8=8.
// Round 12: two orthogonal fixes.
// (1) qkv fused to ONE pass over x: the old 3-pass grid.y layout re-read the
//     8MB x per projection (24MB fetch ~ 4.2us @ 6.3TB/s). One pass reads x
//     once into 64 VGPRs, computes all 3 projections (1536 FMA/thread, only
//     ~0.6us of VALU chip-wide), writes Q/K/V. 64-thread blocks x 512 keep
//     every CU busy. Predicted ~2us.
// (2) attn is transcendental-bound: 134M exps, v_exp_f32 is quarter-rate
//     (8cyc/wave64) -> 6.8us floor on the trans pipe, ~128 of ~160 VALU
//     cyc/chunk. P is truncated to bf16 right after, and l sums the SAME
//     approximated p (ones-row) so common-mode exp error cancels in the
//     normalize. Replace with 2-instr Schraudolph exp2 (v_fma + v_cvt_i32,
//     full-rate, 4cyc): bits = (int)(x*2^23 + (127-0.0347)*2^23), magic
//     centered so log2-err is +-0.05 (zero-mean over frac(s)). Per-chunk
//     VALU 160 -> ~96 cyc; predicted attn ~9 -> ~6us.
// Kept from r6-r11 (all verified): panel V [b][128][16][32] with ones-row 8
// (l = sum(p) on the MFMA pipe), in-register P via permuted key map, 2
// q-tiles/wave (32 q/block, 1024 blocks) amortizing K/V return traffic,
// depth-2 register prefetch, pack via v_perm_b32, fused Wo/residual
// epilogue, split-K 4 waves + LDS combine.
// Non-attn ~84us is fixed harness overhead (0xAA re-poison fills at ~80% of
// HBM peak + restores); the two kernels are the only lever.

#define BB   8
#define CC   64
#define NPIX 4096
#define EE   8
#define BN   (BB*NPIX)        // 32768
#define YSZ  (BB*CC*NPIX)     // 2097152
#define LOG2E 1.4426950408889634f

typedef __attribute__((ext_vector_type(8))) short bf16x8;
typedef __attribute__((ext_vector_type(4))) float f32x4;

__device__ __forceinline__ unsigned short f2bf_rne(float x) {
    unsigned u = __float_as_uint(x);
    u += 0x7FFFu + ((u >> 16) & 1u);
    return (unsigned short)(u >> 16);
}
// dst = [hi16(a), hi16(b)] in one v_perm_b32 (truncation; bias cancels in
// the softmax normalize since l sums the same truncated p via the ones-row).
__device__ __forceinline__ unsigned pack_bf_trunc(float a, float b) {
    return __builtin_amdgcn_perm(__float_as_uint(b), __float_as_uint(a),
                                 0x07060302u);
}
// Schraudolph exp2: piecewise-linear mantissa, error-centered magic.
// (127 - 0.0347) * 2^23 = 1065062131; max relative err ~ +-3.5%, zero-mean.
// 2 full-rate VALU ops vs v_exp_f32's quarter-rate 8 cycles.
__device__ __forceinline__ float fexp2(float x) {
    return __int_as_float((int)fmaf(x, 8388608.f, 1065062131.f));
}

// ---- K1: fused QKV projection, single pass over x ----
// 1 pixel/thread, 64-thread blocks, grid 512 (2 blocks/CU, all CUs busy).
__global__ __launch_bounds__(64) void qkv_kernel(
    const float* __restrict__ x,
    const float* __restrict__ Wk, const float* __restrict__ bk,
    const float* __restrict__ Wq, const float* __restrict__ bq,
    const float* __restrict__ Wv, const float* __restrict__ bv,
    unsigned short* __restrict__ QT, unsigned short* __restrict__ KT,
    unsigned short* __restrict__ VT)
{
    const int bm = blockIdx.x*64 + threadIdx.x;
    const int b  = bm >> 12;
    const int n  = bm & (NPIX-1);
    const float* xb = x + (size_t)b*CC*NPIX + n;

    float xv[CC];
    #pragma unroll
    for (int c = 0; c < CC; ++c) xv[c] = xb[(size_t)c*NPIX];

    // Q (pre-scaled by log2(e) so attn works in exp2 domain)
    {
        union { unsigned short s[8]; uint4 v; } t;
        #pragma unroll
        for (int e = 0; e < EE; ++e) {
            float acc = bq[e];
            #pragma unroll
            for (int c = 0; c < CC; ++c) acc = fmaf(Wq[e*CC+c], xv[c], acc);
            t.s[e] = f2bf_rne(acc * LOG2E);
        }
        *(uint4*)(QT + (size_t)bm*EE) = t.v;
    }
    // K
    {
        union { unsigned short s[8]; uint4 v; } t;
        #pragma unroll
        for (int e = 0; e < EE; ++e) {
            float acc = bk[e];
            #pragma unroll
            for (int c = 0; c < CC; ++c) acc = fmaf(Wk[e*CC+c], xv[c], acc);
            t.s[e] = f2bf_rne(acc);
        }
        *(uint4*)(KT + (size_t)bm*EE) = t.v;
    }
    // V in panel layout: panel p = n>>5; within-row short offset for key
    // c = n&31: quad q(c) block of 8: [0..3]=keys 4q..4q+3, [4..7]=16+4q..+3
    {
        const int p   = n >> 5;
        const int c   = n & 31;
        const int off = ((c & 15) >> 2)*8 + ((c >> 4) << 2) + (c & 3);
        unsigned short* vp = VT + ((size_t)(b*128 + p)*16)*32 + off;
        #pragma unroll
        for (int e = 0; e < EE; ++e) {
            float acc = bv[e];
            #pragma unroll
            for (int c2 = 0; c2 < CC; ++c2) acc = fmaf(Wv[e*CC+c2], xv[c2], acc);
            vp[e*32] = f2bf_rne(acc);
        }
        vp[8*32] = 0x3F80;                         // ones row -> l via GEMM2
    }
}

// ---- K2: flash attention, 2 q-tiles/wave + fused epilogue ----
// Block = 32 queries; 4 waves split the 4096 keys x4. Grid = 8*128 = 1024.
__global__ __launch_bounds__(256, 4) void attn_fused(
    const unsigned short* __restrict__ QT, const unsigned short* __restrict__ KT,
    const unsigned short* __restrict__ VT,
    const float* __restrict__ x, const float* __restrict__ Wo,
    const float* __restrict__ bo, const float* __restrict__ gamma,
    float* __restrict__ out)
{
    __shared__ float OB[3*2*256];  // waves 1..3 x {A,B} x 64 lanes x f32x4
    __shared__ float VL[32*12];    // normalized v per pixel
    __shared__ float Wos[CC*9];    // stride 9: conflict-free epilogue reads
    __shared__ float bos[CC];

    const int tid  = threadIdx.x;
    const int wave = tid >> 6, lane = tid & 63;
    const int quad = lane >> 4, lm = lane & 15;
    const int b  = blockIdx.x >> 7;
    const int m0 = (blockIdx.x & 127) * 32;

    for (int i = tid; i < CC*EE; i += 256) Wos[(i>>3)*9 + (i&7)] = Wo[i];
    if (tid < CC) bos[tid] = bo[tid];

    // B1 operands: only quad0 lanes carry real q rows; others stay zero.
    bf16x8 qfA = {0,0,0,0,0,0,0,0}, qfB = {0,0,0,0,0,0,0,0};
    if (quad == 0) {
        qfA = *(const bf16x8*)(QT + (size_t)(b*NPIX + m0 + lm)*EE);
        qfB = *(const bf16x8*)(QT + (size_t)(b*NPIX + m0 + 16 + lm)*EE);
    }

    f32x4 oaccA = {0.f,0.f,0.f,0.f}, oaccB = {0.f,0.f,0.f,0.f};
    const f32x4 zc = {0.f,0.f,0.f,0.f};

    const unsigned short* Kb = KT + (size_t)b*NPIX*EE;
    const int n_start = wave*1024;                 // split-K: 1024 keys/wave
    // K address is quad-independent: all quads hit the same 256B segment;
    // quads 1..3 hold real K x qf zero rows = 0 contribution.
    const unsigned short* kl = Kb + (size_t)(n_start + lm)*EE;
    // V panel: row clamp (rows 9..15 -> 8; same lines, C rows 9..15 discarded)
    const int lmv = (lm < 9) ? lm : 8;
    const unsigned short* vl = VT + ((size_t)(b*128 + (n_start >> 5))*16 + lmv)*32
                                  + quad*8;

    // 2-deep register pipeline
    bf16x8 kf0a = *(const bf16x8*)(kl);
    bf16x8 kf1a = *(const bf16x8*)(kl + 16*EE);
    bf16x8 vfa  = *(const bf16x8*)(vl);
    bf16x8 kf0b = *(const bf16x8*)(kl + 32*EE);
    bf16x8 kf1b = *(const bf16x8*)(kl + 48*EE);
    bf16x8 vfb  = *(const bf16x8*)(vl + 512);
    kl += 64*EE; vl += 1024;

    #pragma unroll 2
    for (int ch = 0; ch < 32; ++ch) {
        bf16x8 kf0 = kf0a, kf1 = kf1a, vf = vfa;
        kf0a = kf0b; kf1a = kf1b; vfa = vfb;       // ping-pong, no movs
        if (ch < 30) {                             // prefetch chunk ch+2
            kf0b = *(const bf16x8*)(kl);
            kf1b = *(const bf16x8*)(kl + 16*EE);
            vfb  = *(const bf16x8*)(vl);
            kl += 32*EE; vl += 512;
        }

        // S: C-layout lane (quad,lm) reg r = S[key][query];
        // s0: key = 4*quad + r; s1: key = 16 + 4*quad + r.
        f32x4 s0a = __builtin_amdgcn_mfma_f32_16x16x32_bf16(kf0, qfA, zc, 0, 0, 0);
        f32x4 s1a = __builtin_amdgcn_mfma_f32_16x16x32_bf16(kf1, qfA, zc, 0, 0, 0);
        f32x4 s0b = __builtin_amdgcn_mfma_f32_16x16x32_bf16(kf0, qfB, zc, 0, 0, 0);
        f32x4 s1b = __builtin_amdgcn_mfma_f32_16x16x32_bf16(kf1, qfB, zc, 0, 0, 0);

        float a0 = fexp2(s0a.x), a1 = fexp2(s0a.y);
        float a2 = fexp2(s0a.z), a3 = fexp2(s0a.w);
        float a4 = fexp2(s1a.x), a5 = fexp2(s1a.y);
        float a6 = fexp2(s1a.z), a7 = fexp2(s1a.w);
        float b0 = fexp2(s0b.x), b1 = fexp2(s0b.y);
        float b2 = fexp2(s0b.z), b3 = fexp2(s0b.w);
        float b4 = fexp2(s1b.x), b5 = fexp2(s1b.y);
        float b6 = fexp2(s1b.z), b7 = fexp2(s1b.w);

        // B2 fragment IS the C-layout regs under the permuted key map
        // (slot k=quad*8+j -> key quad*4+j (j<4) / 16+quad*4+(j-4)),
        // matching the V panel row layout. Verified r6-r10.
        union { unsigned u[4]; bf16x8 v; } puA, puB;
        puA.u[0] = pack_bf_trunc(a0, a1); puA.u[1] = pack_bf_trunc(a2, a3);
        puA.u[2] = pack_bf_trunc(a4, a5); puA.u[3] = pack_bf_trunc(a6, a7);
        puB.u[0] = pack_bf_trunc(b0, b1); puB.u[1] = pack_bf_trunc(b2, b3);
        puB.u[2] = pack_bf_trunc(b4, b5); puB.u[3] = pack_bf_trunc(b6, b7);
        oaccA = __builtin_amdgcn_mfma_f32_16x16x32_bf16(vf, puA.v, oaccA, 0, 0, 0);
        oaccB = __builtin_amdgcn_mfma_f32_16x16x32_bf16(vf, puB.v, oaccB, 0, 0, 0);
    }

    // cross-wave combine; l rides along in C-row 8 (quad2 lanes, reg .x)
    if (wave != 0) {
        *(f32x4*)(OB + ((size_t)(wave-1)*2 + 0)*256 + lane*4) = oaccA;
        *(f32x4*)(OB + ((size_t)(wave-1)*2 + 1)*256 + lane*4) = oaccB;
    }
    __syncthreads();
    if (wave == 0) {
        f32x4 oA = oaccA, oB = oaccB;
        #pragma unroll
        for (int w = 0; w < 3; ++w) {
            oA += *(f32x4*)(OB + ((size_t)w*2 + 0)*256 + lane*4);
            oB += *(f32x4*)(OB + ((size_t)w*2 + 1)*256 + lane*4);
        }
        float lA = __shfl(oA.x, 32 + lm);          // row 8 = sum of trunc(p)
        float lB = __shfl(oB.x, 32 + lm);
        float invA = 1.f / lA, invB = 1.f / lB;
        if (quad < 2) {                            // rows e = quad*4+reg in 0..7
            f32x4 sA = { oA.x*invA, oA.y*invA, oA.z*invA, oA.w*invA };
            f32x4 sB = { oB.x*invB, oB.y*invB, oB.z*invB, oB.w*invB };
            *(f32x4*)(VL + lm*12 + quad*4)        = sA;
            *(f32x4*)(VL + (16 + lm)*12 + quad*4) = sB;
        }
    }
    __syncthreads();

    // Fused epilogue: 32 px x 64 ch over 256 threads (8 ch each).
    const float g  = gamma[0];
    const int   px = tid & 31;
    const int   cg = tid >> 5;                     // 0..7
    const size_t base = (size_t)b*CC*NPIX + (m0 + px);
    float v[EE];
    #pragma unroll
    for (int e = 0; e < EE; ++e) v[e] = VL[px*12 + e];
    #pragma unroll
    for (int i = 0; i < 8; ++i) {
        const int c = cg*8 + i;
        float o = bos[c];
        #pragma unroll
        for (int e = 0; e < EE; ++e) o += Wos[c*9 + e] * v[e];
        out[(size_t)YSZ + base + (size_t)c*NPIX] = o;
        out[base + (size_t)c*NPIX] = g*o + x[base + (size_t)c*NPIX];
    }
    if (blockIdx.x == 0 && tid == 0) out[2*(size_t)YSZ] = g;  // gamma passthrough
}

extern "C" void kernel_launch(void* const* d_in, const int* in_sizes, int n_in,
                              void* d_out, int out_size, void* d_ws, size_t ws_size,
                              hipStream_t stream) {
    const float* x     = (const float*)d_in[0];
    const float* Wk    = (const float*)d_in[1];
    const float* bk    = (const float*)d_in[2];
    const float* Wq    = (const float*)d_in[3];
    const float* bq    = (const float*)d_in[4];
    const float* Wv    = (const float*)d_in[5];
    const float* bv    = (const float*)d_in[6];
    const float* Wo    = (const float*)d_in[7];
    const float* bo    = (const float*)d_in[8];
    const float* gamma = (const float*)d_in[9];
    float* out = (float*)d_out;

    // ws: QT(512KB) | KT(512KB) | VT(1MB bf16, panelized [b][128][16][32];
    // row 8 = ones, rows 9..15 poison -> only discarded C rows) = 2MB
    unsigned short* QT = (unsigned short*)d_ws;
    unsigned short* KT = QT + (size_t)BN*EE;
    unsigned short* VT = KT + (size_t)BN*EE;

    qkv_kernel<<<BN/64, 64, 0, stream>>>(x, Wk, bk, Wq, bq, Wv, bv, QT, KT, VT);
    attn_fused<<<BB*128, 256, 0, stream>>>(QT, KT, VT, x, Wo, bo, gamma, out);
}

// Round 2
// 109.613 us; speedup vs baseline: 1.0815x; 1.0815x over previous
//
#include <hip/hip_runtime.h>

// Self-attention (SAGAN-style): B=8, C=64, H=W=64 -> N=4096, E=C/8=8.
// Round 13: single-variable A/B. r12's fused qkv (64-thr blocks, 0.5
// waves/SIMD) was an occupancy disaster (-10us); reverted to the r11
// 3-pass qkv (grid.y = proj, 256-thr blocks, 6 waves/CU) that was part of
// the measured 108.8us. KEPT r12's Schraudolph exp2 in attn: 2 full-rate
// VALU ops (v_fma + v_cvt_i32) vs quarter-rate v_exp_f32 (8 cyc). P is
// truncated to bf16 immediately after and l sums the SAME approximated p
// (ones-row), so common-mode exp error cancels in the normalize; absmax
// 0.0098 (passed r12). Per-chunk VALU ~164 -> ~100 cyc; predicted attn
// ~8.8 -> ~5.3us, total ~105-106us. If neutral, attn is not VALU-bound
// and the model gets revised.
// Kept from r6-r11 (all verified): panel V [b][128][16][32] with ones-row 8
// (l = sum(p) on the MFMA pipe), in-register P via permuted key map, 2
// q-tiles/wave (32 q/block, 1024 blocks) amortizing K/V return traffic,
// depth-2 register prefetch, pack via v_perm_b32, fused Wo/residual
// epilogue, split-K 4 waves + LDS combine.
// Non-attn ~84us is fixed harness overhead (0xAA re-poison fills at ~80% of
// HBM peak + restores); the two kernels are the only lever.

#define BB   8
#define CC   64
#define NPIX 4096
#define EE   8
#define BN   (BB*NPIX)        // 32768
#define YSZ  (BB*CC*NPIX)     // 2097152
#define LOG2E 1.4426950408889634f

typedef __attribute__((ext_vector_type(8))) short bf16x8;
typedef __attribute__((ext_vector_type(4))) float f32x4;

__device__ __forceinline__ unsigned short f2bf_rne(float x) {
    unsigned u = __float_as_uint(x);
    u += 0x7FFFu + ((u >> 16) & 1u);
    return (unsigned short)(u >> 16);
}
// dst = [hi16(a), hi16(b)] in one v_perm_b32 (truncation; bias cancels in
// the softmax normalize since l sums the same truncated p via the ones-row).
__device__ __forceinline__ unsigned pack_bf_trunc(float a, float b) {
    return __builtin_amdgcn_perm(__float_as_uint(b), __float_as_uint(a),
                                 0x07060302u);
}
// Schraudolph exp2: piecewise-linear mantissa, error-centered magic.
// (127 - 0.0347) * 2^23 = 1065062131; max relative err ~ +-3.5%, zero-mean.
// 2 full-rate VALU ops vs v_exp_f32's quarter-rate 8 cycles.
__device__ __forceinline__ float fexp2(float x) {
    return __int_as_float((int)fmaf(x, 8388608.f, 1065062131.f));
}

// ---- K1: QKV projection; V written in panel layout (r11 3-pass form) ----
__global__ __launch_bounds__(256) void qkv_kernel(
    const float* __restrict__ x,
    const float* __restrict__ Wk, const float* __restrict__ bk,
    const float* __restrict__ Wq, const float* __restrict__ bq,
    const float* __restrict__ Wv, const float* __restrict__ bv,
    unsigned short* __restrict__ QT, unsigned short* __restrict__ KT,
    unsigned short* __restrict__ VT)
{
    const int proj = blockIdx.y;  // 0=Q, 1=K, 2=V
    const float* W    = (proj == 0) ? Wq : (proj == 1) ? Wk : Wv;
    const float* bias = (proj == 0) ? bq : (proj == 1) ? bk : bv;

    const int bm = blockIdx.x*256 + threadIdx.x;
    const int b  = bm >> 12;
    const int n  = bm & (NPIX-1);
    const float* xb = x + (size_t)b*CC*NPIX + n;

    float xv[CC];
    #pragma unroll
    for (int c = 0; c < CC; ++c) xv[c] = xb[(size_t)c*NPIX];

    float f[EE];
    #pragma unroll
    for (int e = 0; e < EE; ++e) {
        float acc = bias[e];
        #pragma unroll
        for (int c = 0; c < CC; ++c) acc = fmaf(W[e*CC+c], xv[c], acc);
        f[e] = acc;
    }

    if (proj == 0) {
        union { unsigned short s[8]; uint4 v; } t;
        #pragma unroll
        for (int e = 0; e < EE; ++e) t.s[e] = f2bf_rne(f[e] * LOG2E);
        *(uint4*)(QT + (size_t)bm*EE) = t.v;
    } else if (proj == 1) {
        union { unsigned short s[8]; uint4 v; } t;
        #pragma unroll
        for (int e = 0; e < EE; ++e) t.s[e] = f2bf_rne(f[e]);
        *(uint4*)(KT + (size_t)bm*EE) = t.v;
    } else {
        // panel p = n>>5; within-row short offset for key c = n&31:
        // quad q(c) block of 8: [0..3]=keys 4q..4q+3, [4..7]=keys 16+4q..+3
        const int p   = n >> 5;
        const int c   = n & 31;
        const int off = ((c & 15) >> 2)*8 + ((c >> 4) << 2) + (c & 3);
        unsigned short* vp = VT + ((size_t)(b*128 + p)*16)*32 + off;
        #pragma unroll
        for (int e = 0; e < EE; ++e) vp[e*32] = f2bf_rne(f[e]);
        vp[8*32] = 0x3F80;                         // ones row -> l via GEMM2
    }
}

// ---- K2: flash attention, 2 q-tiles/wave + fused epilogue ----
// Block = 32 queries; 4 waves split the 4096 keys x4. Grid = 8*128 = 1024.
__global__ __launch_bounds__(256, 4) void attn_fused(
    const unsigned short* __restrict__ QT, const unsigned short* __restrict__ KT,
    const unsigned short* __restrict__ VT,
    const float* __restrict__ x, const float* __restrict__ Wo,
    const float* __restrict__ bo, const float* __restrict__ gamma,
    float* __restrict__ out)
{
    __shared__ float OB[3*2*256];  // waves 1..3 x {A,B} x 64 lanes x f32x4
    __shared__ float VL[32*12];    // normalized v per pixel
    __shared__ float Wos[CC*9];    // stride 9: conflict-free epilogue reads
    __shared__ float bos[CC];

    const int tid  = threadIdx.x;
    const int wave = tid >> 6, lane = tid & 63;
    const int quad = lane >> 4, lm = lane & 15;
    const int b  = blockIdx.x >> 7;
    const int m0 = (blockIdx.x & 127) * 32;

    for (int i = tid; i < CC*EE; i += 256) Wos[(i>>3)*9 + (i&7)] = Wo[i];
    if (tid < CC) bos[tid] = bo[tid];

    // B1 operands: only quad0 lanes carry real q rows; others stay zero.
    bf16x8 qfA = {0,0,0,0,0,0,0,0}, qfB = {0,0,0,0,0,0,0,0};
    if (quad == 0) {
        qfA = *(const bf16x8*)(QT + (size_t)(b*NPIX + m0 + lm)*EE);
        qfB = *(const bf16x8*)(QT + (size_t)(b*NPIX + m0 + 16 + lm)*EE);
    }

    f32x4 oaccA = {0.f,0.f,0.f,0.f}, oaccB = {0.f,0.f,0.f,0.f};
    const f32x4 zc = {0.f,0.f,0.f,0.f};

    const unsigned short* Kb = KT + (size_t)b*NPIX*EE;
    const int n_start = wave*1024;                 // split-K: 1024 keys/wave
    // K address is quad-independent: all quads hit the same 256B segment;
    // quads 1..3 hold real K x qf zero rows = 0 contribution.
    const unsigned short* kl = Kb + (size_t)(n_start + lm)*EE;
    // V panel: row clamp (rows 9..15 -> 8; same lines, C rows 9..15 discarded)
    const int lmv = (lm < 9) ? lm : 8;
    const unsigned short* vl = VT + ((size_t)(b*128 + (n_start >> 5))*16 + lmv)*32
                                  + quad*8;

    // 2-deep register pipeline
    bf16x8 kf0a = *(const bf16x8*)(kl);
    bf16x8 kf1a = *(const bf16x8*)(kl + 16*EE);
    bf16x8 vfa  = *(const bf16x8*)(vl);
    bf16x8 kf0b = *(const bf16x8*)(kl + 32*EE);
    bf16x8 kf1b = *(const bf16x8*)(kl + 48*EE);
    bf16x8 vfb  = *(const bf16x8*)(vl + 512);
    kl += 64*EE; vl += 1024;

    #pragma unroll 2
    for (int ch = 0; ch < 32; ++ch) {
        bf16x8 kf0 = kf0a, kf1 = kf1a, vf = vfa;
        kf0a = kf0b; kf1a = kf1b; vfa = vfb;       // ping-pong, no movs
        if (ch < 30) {                             // prefetch chunk ch+2
            kf0b = *(const bf16x8*)(kl);
            kf1b = *(const bf16x8*)(kl + 16*EE);
            vfb  = *(const bf16x8*)(vl);
            kl += 32*EE; vl += 512;
        }

        // S: C-layout lane (quad,lm) reg r = S[key][query];
        // s0: key = 4*quad + r; s1: key = 16 + 4*quad + r.
        f32x4 s0a = __builtin_amdgcn_mfma_f32_16x16x32_bf16(kf0, qfA, zc, 0, 0, 0);
        f32x4 s1a = __builtin_amdgcn_mfma_f32_16x16x32_bf16(kf1, qfA, zc, 0, 0, 0);
        f32x4 s0b = __builtin_amdgcn_mfma_f32_16x16x32_bf16(kf0, qfB, zc, 0, 0, 0);
        f32x4 s1b = __builtin_amdgcn_mfma_f32_16x16x32_bf16(kf1, qfB, zc, 0, 0, 0);

        float a0 = fexp2(s0a.x), a1 = fexp2(s0a.y);
        float a2 = fexp2(s0a.z), a3 = fexp2(s0a.w);
        float a4 = fexp2(s1a.x), a5 = fexp2(s1a.y);
        float a6 = fexp2(s1a.z), a7 = fexp2(s1a.w);
        float b0 = fexp2(s0b.x), b1 = fexp2(s0b.y);
        float b2 = fexp2(s0b.z), b3 = fexp2(s0b.w);
        float b4 = fexp2(s1b.x), b5 = fexp2(s1b.y);
        float b6 = fexp2(s1b.z), b7 = fexp2(s1b.w);

        // B2 fragment IS the C-layout regs under the permuted key map
        // (slot k=quad*8+j -> key quad*4+j (j<4) / 16+quad*4+(j-4)),
        // matching the V panel row layout. Verified r6-r10.
        union { unsigned u[4]; bf16x8 v; } puA, puB;
        puA.u[0] = pack_bf_trunc(a0, a1); puA.u[1] = pack_bf_trunc(a2, a3);
        puA.u[2] = pack_bf_trunc(a4, a5); puA.u[3] = pack_bf_trunc(a6, a7);
        puB.u[0] = pack_bf_trunc(b0, b1); puB.u[1] = pack_bf_trunc(b2, b3);
        puB.u[2] = pack_bf_trunc(b4, b5); puB.u[3] = pack_bf_trunc(b6, b7);
        oaccA = __builtin_amdgcn_mfma_f32_16x16x32_bf16(vf, puA.v, oaccA, 0, 0, 0);
        oaccB = __builtin_amdgcn_mfma_f32_16x16x32_bf16(vf, puB.v, oaccB, 0, 0, 0);
    }

    // cross-wave combine; l rides along in C-row 8 (quad2 lanes, reg .x)
    if (wave != 0) {
        *(f32x4*)(OB + ((size_t)(wave-1)*2 + 0)*256 + lane*4) = oaccA;
        *(f32x4*)(OB + ((size_t)(wave-1)*2 + 1)*256 + lane*4) = oaccB;
    }
    __syncthreads();
    if (wave == 0) {
        f32x4 oA = oaccA, oB = oaccB;
        #pragma unroll
        for (int w = 0; w < 3; ++w) {
            oA += *(f32x4*)(OB + ((size_t)w*2 + 0)*256 + lane*4);
            oB += *(f32x4*)(OB + ((size_t)w*2 + 1)*256 + lane*4);
        }
        float lA = __shfl(oA.x, 32 + lm);          // row 8 = sum of trunc(p)
        float lB = __shfl(oB.x, 32 + lm);
        float invA = 1.f / lA, invB = 1.f / lB;
        if (quad < 2) {                            // rows e = quad*4+reg in 0..7
            f32x4 sA = { oA.x*invA, oA.y*invA, oA.z*invA, oA.w*invA };
            f32x4 sB = { oB.x*invB, oB.y*invB, oB.z*invB, oB.w*invB };
            *(f32x4*)(VL + lm*12 + quad*4)        = sA;
            *(f32x4*)(VL + (16 + lm)*12 + quad*4) = sB;
        }
    }
    __syncthreads();

    // Fused epilogue: 32 px x 64 ch over 256 threads (8 ch each).
    const float g  = gamma[0];
    const int   px = tid & 31;
    const int   cg = tid >> 5;                     // 0..7
    const size_t base = (size_t)b*CC*NPIX + (m0 + px);
    float v[EE];
    #pragma unroll
    for (int e = 0; e < EE; ++e) v[e] = VL[px*12 + e];
    #pragma unroll
    for (int i = 0; i < 8; ++i) {
        const int c = cg*8 + i;
        float o = bos[c];
        #pragma unroll
        for (int e = 0; e < EE; ++e) o += Wos[c*9 + e] * v[e];
        out[(size_t)YSZ + base + (size_t)c*NPIX] = o;
        out[base + (size_t)c*NPIX] = g*o + x[base + (size_t)c*NPIX];
    }
    if (blockIdx.x == 0 && tid == 0) out[2*(size_t)YSZ] = g;  // gamma passthrough
}

extern "C" void kernel_launch(void* const* d_in, const int* in_sizes, int n_in,
                              void* d_out, int out_size, void* d_ws, size_t ws_size,
                              hipStream_t stream) {
    const float* x     = (const float*)d_in[0];
    const float* Wk    = (const float*)d_in[1];
    const float* bk    = (const float*)d_in[2];
    const float* Wq    = (const float*)d_in[3];
    const float* bq    = (const float*)d_in[4];
    const float* Wv    = (const float*)d_in[5];
    const float* bv    = (const float*)d_in[6];
    const float* Wo    = (const float*)d_in[7];
    const float* bo    = (const float*)d_in[8];
    const float* gamma = (const float*)d_in[9];
    float* out = (float*)d_out;

    // ws: QT(512KB) | KT(512KB) | VT(1MB bf16, panelized [b][128][16][32];
    // row 8 = ones, rows 9..15 poison -> only discarded C rows) = 2MB
    unsigned short* QT = (unsigned short*)d_ws;
    unsigned short* KT = QT + (size_t)BN*EE;
    unsigned short* VT = KT + (size_t)BN*EE;

    qkv_kernel<<<dim3(BN/256, 3), 256, 0, stream>>>(x, Wk, bk, Wq, bq, Wv, bv, QT, KT, VT);
    attn_fused<<<BB*128, 256, 0, stream>>>(QT, KT, VT, x, Wo, bo, gamma, out);
}

// Round 3
// 107.288 us; speedup vs baseline: 1.1050x; 1.0217x over previous
//
#include <hip/hip_runtime.h>

// Self-attention (SAGAN-style): B=8, C=64, H=W=64 -> N=4096, E=C/8=8.
// Round 14: attn K-return de-duplication. r13's fexp2 A/B was NEUTRAL ->
// attn is not VALU-issue-bound; model moves to VMEM data return. Old kf
// loads were quad-replicated (all 4 quads fetch the same 256B segment; only
// quad0's data survives the B-zero mask) -> 75% of K return discarded.
// New: ONE full-wave K load per 64 keys (lane l -> key n+l, 1KB all useful)
// + FOUR pre-built Q fragments qA[g]/qB[g] (Q in quad-g lanes, zeros
// elsewhere). Group-g MFMA mfma(kf, q[g]) pulls its A rows from quad-g
// lanes = keys 16g..16g+15; output reg map key = 16g + 4*quad + r is the
// same s0/s1 convention as r6-r13, so the verified pack->PV permuted key
// map is unchanged: panel0 <- (s0,s1), panel1 <- (s2,s3). Per 64 keys:
// VMEM 6 loads/6KB -> 3 loads/3KB, MFMA count unchanged (12), exp count
// unchanged. Predicted attn -30-40% if VMEM-return-bound; total ~105-107us.
// Kept: r13 3-pass qkv (known-good), fexp2 (Schraudolph, absmax 0.0098),
// panel V [b][128][16][32] with ones-row 8 (l = sum(p) on the MFMA pipe),
// in-register P, 2 q-tiles/wave, depth-2 register prefetch, v_perm pack,
// fused Wo/residual epilogue, split-K 4 waves + LDS combine.
// Non-attn ~84us is fixed harness overhead (0xAA re-poison fills at ~80% of
// HBM peak); the two kernels are the only lever (~25.6us budget).

#define BB   8
#define CC   64
#define NPIX 4096
#define EE   8
#define BN   (BB*NPIX)        // 32768
#define YSZ  (BB*CC*NPIX)     // 2097152
#define LOG2E 1.4426950408889634f

typedef __attribute__((ext_vector_type(8))) short bf16x8;
typedef __attribute__((ext_vector_type(4))) float f32x4;

__device__ __forceinline__ unsigned short f2bf_rne(float x) {
    unsigned u = __float_as_uint(x);
    u += 0x7FFFu + ((u >> 16) & 1u);
    return (unsigned short)(u >> 16);
}
// dst = [hi16(a), hi16(b)] in one v_perm_b32 (truncation; bias cancels in
// the softmax normalize since l sums the same truncated p via the ones-row).
__device__ __forceinline__ unsigned pack_bf_trunc(float a, float b) {
    return __builtin_amdgcn_perm(__float_as_uint(b), __float_as_uint(a),
                                 0x07060302u);
}
// Schraudolph exp2: piecewise-linear mantissa, error-centered magic.
// (127 - 0.0347) * 2^23 = 1065062131; max relative err ~ +-3.5%, zero-mean.
// 2 full-rate VALU ops vs v_exp_f32's quarter-rate 8 cycles.
__device__ __forceinline__ float fexp2(float x) {
    return __int_as_float((int)fmaf(x, 8388608.f, 1065062131.f));
}

// ---- K1: QKV projection; V written in panel layout (r11/r13 3-pass) ----
__global__ __launch_bounds__(256) void qkv_kernel(
    const float* __restrict__ x,
    const float* __restrict__ Wk, const float* __restrict__ bk,
    const float* __restrict__ Wq, const float* __restrict__ bq,
    const float* __restrict__ Wv, const float* __restrict__ bv,
    unsigned short* __restrict__ QT, unsigned short* __restrict__ KT,
    unsigned short* __restrict__ VT)
{
    const int proj = blockIdx.y;  // 0=Q, 1=K, 2=V
    const float* W    = (proj == 0) ? Wq : (proj == 1) ? Wk : Wv;
    const float* bias = (proj == 0) ? bq : (proj == 1) ? bk : bv;

    const int bm = blockIdx.x*256 + threadIdx.x;
    const int b  = bm >> 12;
    const int n  = bm & (NPIX-1);
    const float* xb = x + (size_t)b*CC*NPIX + n;

    float xv[CC];
    #pragma unroll
    for (int c = 0; c < CC; ++c) xv[c] = xb[(size_t)c*NPIX];

    float f[EE];
    #pragma unroll
    for (int e = 0; e < EE; ++e) {
        float acc = bias[e];
        #pragma unroll
        for (int c = 0; c < CC; ++c) acc = fmaf(W[e*CC+c], xv[c], acc);
        f[e] = acc;
    }

    if (proj == 0) {
        union { unsigned short s[8]; uint4 v; } t;
        #pragma unroll
        for (int e = 0; e < EE; ++e) t.s[e] = f2bf_rne(f[e] * LOG2E);
        *(uint4*)(QT + (size_t)bm*EE) = t.v;
    } else if (proj == 1) {
        union { unsigned short s[8]; uint4 v; } t;
        #pragma unroll
        for (int e = 0; e < EE; ++e) t.s[e] = f2bf_rne(f[e]);
        *(uint4*)(KT + (size_t)bm*EE) = t.v;
    } else {
        // panel p = n>>5; within-row short offset for key c = n&31:
        // quad q(c) block of 8: [0..3]=keys 4q..4q+3, [4..7]=keys 16+4q..+3
        const int p   = n >> 5;
        const int c   = n & 31;
        const int off = ((c & 15) >> 2)*8 + ((c >> 4) << 2) + (c & 3);
        unsigned short* vp = VT + ((size_t)(b*128 + p)*16)*32 + off;
        #pragma unroll
        for (int e = 0; e < EE; ++e) vp[e*32] = f2bf_rne(f[e]);
        vp[8*32] = 0x3F80;                         // ones row -> l via GEMM2
    }
}

// ---- K2: flash attention, 64-key chunks, dedup'd K loads ----
// Block = 32 queries; 4 waves split the 4096 keys x4. Grid = 8*128 = 1024.
__global__ __launch_bounds__(256, 4) void attn_fused(
    const unsigned short* __restrict__ QT, const unsigned short* __restrict__ KT,
    const unsigned short* __restrict__ VT,
    const float* __restrict__ x, const float* __restrict__ Wo,
    const float* __restrict__ bo, const float* __restrict__ gamma,
    float* __restrict__ out)
{
    __shared__ float OB[3*2*256];  // waves 1..3 x {A,B} x 64 lanes x f32x4
    __shared__ float VL[32*12];    // normalized v per pixel
    __shared__ float Wos[CC*9];    // stride 9: conflict-free epilogue reads
    __shared__ float bos[CC];

    const int tid  = threadIdx.x;
    const int wave = tid >> 6, lane = tid & 63;
    const int quad = lane >> 4, lm = lane & 15;
    const int b  = blockIdx.x >> 7;
    const int m0 = (blockIdx.x & 127) * 32;

    for (int i = tid; i < CC*EE; i += 256) Wos[(i>>3)*9 + (i&7)] = Wo[i];
    if (tid < CC) bos[tid] = bo[tid];

    // Q fragments per key-group g: Q rows in quad-g lanes, zeros elsewhere.
    // Group-g S-MFMA mfma(kf, q[g]) reads A only from quad-g lanes (B zero
    // in other k-slots) = keys 16g..16g+15 of the 64-key kf load.
    const bf16x8 kz = {0,0,0,0,0,0,0,0};
    bf16x8 qtA = *(const bf16x8*)(QT + (size_t)(b*NPIX + m0 + lm)*EE);
    bf16x8 qtB = *(const bf16x8*)(QT + (size_t)(b*NPIX + m0 + 16 + lm)*EE);
    bf16x8 qA[4], qB[4];
    #pragma unroll
    for (int g = 0; g < 4; ++g) {
        qA[g] = (quad == g) ? qtA : kz;
        qB[g] = (quad == g) ? qtB : kz;
    }

    f32x4 oaccA = {0.f,0.f,0.f,0.f}, oaccB = {0.f,0.f,0.f,0.f};
    const f32x4 zc = {0.f,0.f,0.f,0.f};

    const unsigned short* Kb = KT + (size_t)b*NPIX*EE;
    const int n_start = wave*1024;                 // split-K: 1024 keys/wave
    // Full-wave K load: lane l -> key n_start + l (1KB coalesced, 0 waste).
    const unsigned short* kl = Kb + (size_t)(n_start + lane)*EE;
    // V panel: row clamp (rows 9..15 -> 8; same lines, C rows 9..15 discarded)
    const int lmv = (lm < 9) ? lm : 8;
    const unsigned short* vl = VT + ((size_t)(b*128 + (n_start >> 5))*16 + lmv)*32
                                  + quad*8;

    // 2-deep register pipeline over 16 chunks of 64 keys
    bf16x8 kfa  = *(const bf16x8*)(kl);
    bf16x8 vf0a = *(const bf16x8*)(vl);
    bf16x8 vf1a = *(const bf16x8*)(vl + 512);
    bf16x8 kfb  = *(const bf16x8*)(kl + 64*EE);
    bf16x8 vf0b = *(const bf16x8*)(vl + 1024);
    bf16x8 vf1b = *(const bf16x8*)(vl + 1536);
    kl += 128*EE; vl += 2048;

    #pragma unroll 2
    for (int ch = 0; ch < 16; ++ch) {
        bf16x8 kf = kfa, vf0 = vf0a, vf1 = vf1a;
        kfa = kfb; vf0a = vf0b; vf1a = vf1b;       // ping-pong, no movs
        if (ch < 14) {                             // prefetch chunk ch+2
            kfb  = *(const bf16x8*)(kl);
            vf0b = *(const bf16x8*)(vl);
            vf1b = *(const bf16x8*)(vl + 512);
            kl += 64*EE; vl += 1024;
        }

        // ---- tile A ----
        // s_g reg r = S[key 16g + 4*quad + r][query m0+lm]
        f32x4 s0a = __builtin_amdgcn_mfma_f32_16x16x32_bf16(kf, qA[0], zc, 0, 0, 0);
        f32x4 s1a = __builtin_amdgcn_mfma_f32_16x16x32_bf16(kf, qA[1], zc, 0, 0, 0);
        f32x4 s2a = __builtin_amdgcn_mfma_f32_16x16x32_bf16(kf, qA[2], zc, 0, 0, 0);
        f32x4 s3a = __builtin_amdgcn_mfma_f32_16x16x32_bf16(kf, qA[3], zc, 0, 0, 0);
        {
            float a0 = fexp2(s0a.x), a1 = fexp2(s0a.y);
            float a2 = fexp2(s0a.z), a3 = fexp2(s0a.w);
            float a4 = fexp2(s1a.x), a5 = fexp2(s1a.y);
            float a6 = fexp2(s1a.z), a7 = fexp2(s1a.w);
            float c0 = fexp2(s2a.x), c1 = fexp2(s2a.y);
            float c2 = fexp2(s2a.z), c3 = fexp2(s2a.w);
            float c4 = fexp2(s3a.x), c5 = fexp2(s3a.y);
            float c6 = fexp2(s3a.z), c7 = fexp2(s3a.w);
            // B2 fragment IS the C-layout regs under the permuted key map
            // (slot k=quad*8+j -> key quad*4+j (j<4) / 16+quad*4+(j-4)),
            // matching the V panel row layout. Verified r6-r13.
            union { unsigned u[4]; bf16x8 v; } p0, p1;
            p0.u[0] = pack_bf_trunc(a0, a1); p0.u[1] = pack_bf_trunc(a2, a3);
            p0.u[2] = pack_bf_trunc(a4, a5); p0.u[3] = pack_bf_trunc(a6, a7);
            p1.u[0] = pack_bf_trunc(c0, c1); p1.u[1] = pack_bf_trunc(c2, c3);
            p1.u[2] = pack_bf_trunc(c4, c5); p1.u[3] = pack_bf_trunc(c6, c7);
            oaccA = __builtin_amdgcn_mfma_f32_16x16x32_bf16(vf0, p0.v, oaccA, 0, 0, 0);
            oaccA = __builtin_amdgcn_mfma_f32_16x16x32_bf16(vf1, p1.v, oaccA, 0, 0, 0);
        }
        // ---- tile B ----
        f32x4 s0b = __builtin_amdgcn_mfma_f32_16x16x32_bf16(kf, qB[0], zc, 0, 0, 0);
        f32x4 s1b = __builtin_amdgcn_mfma_f32_16x16x32_bf16(kf, qB[1], zc, 0, 0, 0);
        f32x4 s2b = __builtin_amdgcn_mfma_f32_16x16x32_bf16(kf, qB[2], zc, 0, 0, 0);
        f32x4 s3b = __builtin_amdgcn_mfma_f32_16x16x32_bf16(kf, qB[3], zc, 0, 0, 0);
        {
            float a0 = fexp2(s0b.x), a1 = fexp2(s0b.y);
            float a2 = fexp2(s0b.z), a3 = fexp2(s0b.w);
            float a4 = fexp2(s1b.x), a5 = fexp2(s1b.y);
            float a6 = fexp2(s1b.z), a7 = fexp2(s1b.w);
            float c0 = fexp2(s2b.x), c1 = fexp2(s2b.y);
            float c2 = fexp2(s2b.z), c3 = fexp2(s2b.w);
            float c4 = fexp2(s3b.x), c5 = fexp2(s3b.y);
            float c6 = fexp2(s3b.z), c7 = fexp2(s3b.w);
            union { unsigned u[4]; bf16x8 v; } p0, p1;
            p0.u[0] = pack_bf_trunc(a0, a1); p0.u[1] = pack_bf_trunc(a2, a3);
            p0.u[2] = pack_bf_trunc(a4, a5); p0.u[3] = pack_bf_trunc(a6, a7);
            p1.u[0] = pack_bf_trunc(c0, c1); p1.u[1] = pack_bf_trunc(c2, c3);
            p1.u[2] = pack_bf_trunc(c4, c5); p1.u[3] = pack_bf_trunc(c6, c7);
            oaccB = __builtin_amdgcn_mfma_f32_16x16x32_bf16(vf0, p0.v, oaccB, 0, 0, 0);
            oaccB = __builtin_amdgcn_mfma_f32_16x16x32_bf16(vf1, p1.v, oaccB, 0, 0, 0);
        }
    }

    // cross-wave combine; l rides along in C-row 8 (quad2 lanes, reg .x)
    if (wave != 0) {
        *(f32x4*)(OB + ((size_t)(wave-1)*2 + 0)*256 + lane*4) = oaccA;
        *(f32x4*)(OB + ((size_t)(wave-1)*2 + 1)*256 + lane*4) = oaccB;
    }
    __syncthreads();
    if (wave == 0) {
        f32x4 oA = oaccA, oB = oaccB;
        #pragma unroll
        for (int w = 0; w < 3; ++w) {
            oA += *(f32x4*)(OB + ((size_t)w*2 + 0)*256 + lane*4);
            oB += *(f32x4*)(OB + ((size_t)w*2 + 1)*256 + lane*4);
        }
        float lA = __shfl(oA.x, 32 + lm);          // row 8 = sum of trunc(p)
        float lB = __shfl(oB.x, 32 + lm);
        float invA = 1.f / lA, invB = 1.f / lB;
        if (quad < 2) {                            // rows e = quad*4+reg in 0..7
            f32x4 sA = { oA.x*invA, oA.y*invA, oA.z*invA, oA.w*invA };
            f32x4 sB = { oB.x*invB, oB.y*invB, oB.z*invB, oB.w*invB };
            *(f32x4*)(VL + lm*12 + quad*4)        = sA;
            *(f32x4*)(VL + (16 + lm)*12 + quad*4) = sB;
        }
    }
    __syncthreads();

    // Fused epilogue: 32 px x 64 ch over 256 threads (8 ch each).
    const float g  = gamma[0];
    const int   px = tid & 31;
    const int   cg = tid >> 5;                     // 0..7
    const size_t base = (size_t)b*CC*NPIX + (m0 + px);
    float v[EE];
    #pragma unroll
    for (int e = 0; e < EE; ++e) v[e] = VL[px*12 + e];
    #pragma unroll
    for (int i = 0; i < 8; ++i) {
        const int c = cg*8 + i;
        float o = bos[c];
        #pragma unroll
        for (int e = 0; e < EE; ++e) o += Wos[c*9 + e] * v[e];
        out[(size_t)YSZ + base + (size_t)c*NPIX] = o;
        out[base + (size_t)c*NPIX] = g*o + x[base + (size_t)c*NPIX];
    }
    if (blockIdx.x == 0 && tid == 0) out[2*(size_t)YSZ] = g;  // gamma passthrough
}

extern "C" void kernel_launch(void* const* d_in, const int* in_sizes, int n_in,
                              void* d_out, int out_size, void* d_ws, size_t ws_size,
                              hipStream_t stream) {
    const float* x     = (const float*)d_in[0];
    const float* Wk    = (const float*)d_in[1];
    const float* bk    = (const float*)d_in[2];
    const float* Wq    = (const float*)d_in[3];
    const float* bq    = (const float*)d_in[4];
    const float* Wv    = (const float*)d_in[5];
    const float* bv    = (const float*)d_in[6];
    const float* Wo    = (const float*)d_in[7];
    const float* bo    = (const float*)d_in[8];
    const float* gamma = (const float*)d_in[9];
    float* out = (float*)d_out;

    // ws: QT(512KB) | KT(512KB) | VT(1MB bf16, panelized [b][128][16][32];
    // row 8 = ones, rows 9..15 poison -> only discarded C rows) = 2MB
    unsigned short* QT = (unsigned short*)d_ws;
    unsigned short* KT = QT + (size_t)BN*EE;
    unsigned short* VT = KT + (size_t)BN*EE;

    qkv_kernel<<<dim3(BN/256, 3), 256, 0, stream>>>(x, Wk, bk, Wq, bq, Wv, bv, QT, KT, VT);
    attn_fused<<<BB*128, 256, 0, stream>>>(QT, KT, VT, x, Wo, bo, gamma, out);
}